// Round 14
// baseline (926.879 us; speedup 1.0000x reference)
//
#include <hip/hip_runtime.h>
#include <hip/hip_bf16.h>

typedef _Float16 f16;
typedef f16   f16x8 __attribute__((ext_vector_type(8)));
typedef float f32x4 __attribute__((ext_vector_type(4)));

#define HW 36864      /* 192*192 */
#define TS 9437184    /* 256*36864 : per-plane per-batch elements */

// ---------------------------------------------------------------------------
// Pre-kernel: W (fp32 256x256) -> 3 fp16 planes: Wq, Wk, Wv
// ---------------------------------------------------------------------------
__global__ __launch_bounds__(256) void convert_w_kernel(
    const float* __restrict__ wq, const float* __restrict__ wk,
    const float* __restrict__ wv, f16* __restrict__ wp) {
  int i = blockIdx.x * 256 + threadIdx.x;  // 0 .. 65535
  wp[i]             = (f16)wq[i];
  wp[65536 + i]     = (f16)wk[i];
  wp[2 * 65536 + i] = (f16)wv[i];
}

// ---------------------------------------------------------------------------
// Stage 1: 1x1 conv GEMM  out[o,n] = sum_i W[o,i] x[i,n] + b[o]
// v5 (R13 post-mortem: fp32-in-LDS forced 128 scalar ds_read_b32 + cvt per
// wave per tile, 28.3M conflicts, MfmaUtil 15% -> LDS-throughput-bound):
//  - Register-staged transpose, SMALL footprint: ISSUE = 8 float4 (32 VGPR),
//    COMMIT converts to f16 and writes Y[n][i] (32KB/tile, double-buffered).
//  - 16B-block swizzle blk' = (i>>3) ^ (n&7): commit writes are a bijection
//    onto each 512B row (4-cyc floor, no conflict); fragment = ONE
//    ds_read_b128 (8 lanes/slot = b128 floor). 16 b128/tile/wave vs 128 b32.
//  - T14 order: ISSUE(t+1) -> COMPUTE(t) -> COMMIT(t+1) -> barrier.
//  - Flat tile decode: grid 512 x 27 tiles (13824 = 24 bt x 576), no tail.
// 512 thr (8 waves: foq=wv>>1 x fnp=wv&1), LDS 64KB, bounds(512,4): VGPR<=128
// -> 2 blocks/CU. acc[4][2]=32 regs; peak live ~110 (R12's spill was rv[16]+
// acc[4][4] = 128 forced).
// ---------------------------------------------------------------------------
__global__ __launch_bounds__(512, 4) void conv1x1_kernel(
    const float* __restrict__ xq, const float* __restrict__ xk, const float* __restrict__ xv,
    const f16* __restrict__ wp,
    const float* __restrict__ bq, const float* __restrict__ bk, const float* __restrict__ bv,
    f16* __restrict__ qkv) {
  const int tid = threadIdx.x;
  const int l   = tid & 63;
  const int wv  = tid >> 6;          // 0..7
  const int lr  = l & 15, lg = l >> 4;
  const int fnp = wv & 1;            // fn pair {2*fnp, 2*fnp+1}
  const int foq = wv >> 1;           // fo quad {4*foq .. 4*foq+3}

  __shared__ __align__(16) char Y[2][32768];   // f16 [n=64][i=256], swizzled

  const int a   = tid & 63;          // i-block: i0 = 4a
  const int nb0 = tid >> 6;          // job0 n-block; job1 = nb0+8
  const int tg0 = blockIdx.x * 27;

  float4 rv[8];

  auto ISSUE = [&](int tg) {
    const int bt = tg / 576, tl = tg - bt * 576;
    const int b = bt / 3, t = bt - b * 3;
    const float* __restrict__ in =
        ((t == 0) ? xq : (t == 1 ? xk : xv)) + (size_t)b * TS;
    const int n0 = tl * 64;
    const int i0 = 4 * a;
#pragma unroll
    for (int j = 0; j < 4; ++j)
      rv[j] = *(const float4*)(in + (size_t)(i0 + j) * HW + n0 + 4 * nb0);
#pragma unroll
    for (int j = 0; j < 4; ++j)
      rv[4 + j] = *(const float4*)(in + (size_t)(i0 + j) * HW + n0 + 4 * (nb0 + 8));
  };

  auto COMMIT = [&](int bufi) {
    char* bp = Y[bufi];
#pragma unroll
    for (int J = 0; J < 2; ++J) {
#pragma unroll
      for (int d = 0; d < 4; ++d) {
        const int n = 4 * (nb0 + 8 * J) + d;
        union { f16 h[4]; unsigned long long u; } p;
#pragma unroll
        for (int j = 0; j < 4; ++j) p.h[j] = (f16)((&rv[4 * J + j].x)[d]);
        *(unsigned long long*)(bp + n * 512 + (((a >> 1) ^ (n & 7)) << 4) + ((a & 1) << 3)) = p.u;
      }
    }
  };

  ISSUE(tg0);
  COMMIT(0);
  __syncthreads();

  int cur = 0;
  for (int tt = 0; tt < 27; ++tt) {
    const int tg = tg0 + tt;
    if (tt < 26) ISSUE(tg + 1);      // loads fly under COMPUTE

    const int bt = tg / 576, tl = tg - bt * 576;
    const int b = bt / 3, t = bt - b * 3;
    const f16* __restrict__ W = wp + t * 65536;
    const float* __restrict__ bias = (t == 0) ? bq : (t == 1 ? bk : bv);
    f16* __restrict__ outp = qkv + (size_t)(b * 3 + t) * TS;
    const int n0 = tl * 64;
    const char* __restrict__ Yc = Y[cur];

    f32x4 acc[4][2];
#pragma unroll
    for (int ff = 0; ff < 4; ++ff)
#pragma unroll
      for (int e = 0; e < 2; ++e) acc[ff][e] = (f32x4){0.f, 0.f, 0.f, 0.f};

#pragma unroll
    for (int ks = 0; ks < 8; ++ks) {
      f16x8 bx[2];
#pragma unroll
      for (int e = 0; e < 2; ++e) {
        const int n = lr + 16 * (2 * fnp + e);
        bx[e] = *(const f16x8*)(Yc + n * 512 + (((4 * ks + lg) ^ (n & 7)) << 4));
      }
      f16x8 aw[4];
#pragma unroll
      for (int ff = 0; ff < 4; ++ff)
        aw[ff] = *(const f16x8*)(W + ((foq * 4 + ff) * 16 + lr) * 256 + ks * 32 + lg * 8);
#pragma unroll
      for (int ff = 0; ff < 4; ++ff)
#pragma unroll
        for (int e = 0; e < 2; ++e)
          acc[ff][e] = __builtin_amdgcn_mfma_f32_16x16x32_f16(aw[ff], bx[e], acc[ff][e], 0, 0, 0);
    }

    // epilogue: C layout col n = lane&15, row o = 4*(lane>>4)+reg
#pragma unroll
    for (int ff = 0; ff < 4; ++ff) {
      const int orow = foq * 64 + ff * 16 + lg * 4;
#pragma unroll
      for (int e = 0; e < 2; ++e) {
        const int n = n0 + 16 * (2 * fnp + e) + lr;
#pragma unroll
        for (int r = 0; r < 4; ++r)
          outp[(size_t)(orow + r) * HW + n] = (f16)(acc[ff][e][r] + bias[orow + r]);
      }
    }

    if (tt < 26) COMMIT(cur ^ 1);    // waits prefetched rv, writes next buf
    __syncthreads();
    cur ^= 1;
  }
}

// ---------------------------------------------------------------------------
// Stage 2: attention, 768 threads (12 waves), one block per (b,c).
// blockIdx.x = b*256 + c. [K stage + issue aq/vp] B1 [QK^T, softmax, Pf]
// B2 [Vt write] B3 [PV]. LDS 153.6 KB -> 1 block/CU. (~175us — untouched.)
// ---------------------------------------------------------------------------
__global__ __launch_bounds__(768) void attn_kernel(
    const f16* __restrict__ qkv, float* __restrict__ outb) {
  const int c2  = blockIdx.x;
  const int b   = c2 >> 8;
  const int c   = c2 & 255;
  const int tid = threadIdx.x;
  const int l   = tid & 63;
  const int wv  = tid >> 6;          // 0..11  == q-tile index
  const int lr  = l & 15, lg = l >> 4;

  const f16* __restrict__ qb = qkv + (size_t)(b * 3) * TS;
  const f16* __restrict__ q = qb + (size_t)c * HW;
  const f16* __restrict__ k = qb + (size_t)TS + (size_t)c * HW;
  const f16* __restrict__ v = qb + 2 * (size_t)TS + (size_t)c * HW;
  float* __restrict__ outc = outb + (size_t)b * TS + (size_t)c * HW;

  __shared__ f16 KA[192][200];   // phase1: K [g][w]   phase2: V^T [w][g]
  __shared__ f16 Pf[192][200];   // normalized P [h][g]

  const int h0 = wv * 16;

  // ---- T14 issue-early: Q fragments (consumed in QK^T)
  f16x8 aq[6];
#pragma unroll
  for (int ks = 0; ks < 6; ++ks)
    aq[ks] = *(const f16x8*)(q + (h0 + lr) * 192 + ks * 32 + lg * 8);

  // ---- T14 issue-early: scattered V-gather into regs (written to LDS later)
  const int gA = (tid % 24) * 8, wA = (tid / 24) * 4;   // job A: all threads
  const int jB = tid + 768;                              // job B: tid < 384
  const int gB = (jB % 24) * 8, wB = (jB / 24) * 4;
  uint2 vpA[8], vpB[8];
#pragma unroll
  for (int j = 0; j < 8; ++j) vpA[j] = *(const uint2*)(v + (gA + j) * 192 + wA);
  if (tid < 384) {
#pragma unroll
    for (int j = 0; j < 8; ++j) vpB[j] = *(const uint2*)(v + (gB + j) * 192 + wB);
  }

  // ---- stage K -> KA (16B chunks, coalesced; 4608 = 768*6)
#pragma unroll
  for (int jj = 0; jj < 6; ++jj) {
    int id = tid + jj * 768;
    int g = id / 24, wo = id % 24;
    *(f16x8*)&KA[g][wo * 8] = *(const f16x8*)(k + g * 192 + wo * 8);
  }
  __syncthreads();                              // B1: K visible

  {
    f32x4 S[12];
#pragma unroll
    for (int fg = 0; fg < 12; ++fg) S[fg] = (f32x4){0.f, 0.f, 0.f, 0.f};
#pragma unroll
    for (int ks = 0; ks < 6; ++ks)
#pragma unroll
      for (int fg = 0; fg < 12; ++fg) {
        f16x8 bk_ = *(const f16x8*)&KA[16 * fg + lr][ks * 32 + lg * 8];
        S[fg] = __builtin_amdgcn_mfma_f32_16x16x32_f16(aq[ks], bk_, S[fg], 0, 0, 0);
      }

    // exact softmax per row (row = 4*lg + r; 16 lanes lr hold g-chunks),
    // normalize, store to Pf in [h][g] layout (C-layout-native scatter).
#pragma unroll
    for (int r = 0; r < 4; ++r) {
      float m = S[0][r];
#pragma unroll
      for (int fg = 1; fg < 12; ++fg) m = fmaxf(m, S[fg][r]);
      m = fmaxf(m, __shfl_xor(m, 1));
      m = fmaxf(m, __shfl_xor(m, 2));
      m = fmaxf(m, __shfl_xor(m, 4));
      m = fmaxf(m, __shfl_xor(m, 8));
      float s = 0.f;
#pragma unroll
      for (int fg = 0; fg < 12; ++fg) {
        float e = __expf(S[fg][r] - m);
        S[fg][r] = e;
        s += e;
      }
      s += __shfl_xor(s, 1);
      s += __shfl_xor(s, 2);
      s += __shfl_xor(s, 4);
      s += __shfl_xor(s, 8);
      float rs = 1.f / s;
#pragma unroll
      for (int fg = 0; fg < 12; ++fg)
        Pf[h0 + lg * 4 + r][16 * fg + lr] = (f16)(S[fg][r] * rs);
    }
  }
  __syncthreads();                              // B2: all KA reads done

  // ---- write V^T into KA from the preloaded regs (conflict-free b128 rows)
  {
#pragma unroll
    for (int qd = 0; qd < 4; ++qd) {
      union { unsigned short s[8]; f16x8 vec; } u;
#pragma unroll
      for (int j = 0; j < 8; ++j) u.s[j] = ((const unsigned short*)&vpA[j])[qd];
      *(f16x8*)&KA[wA + qd][gA] = u.vec;
    }
    if (tid < 384) {
#pragma unroll
      for (int qd = 0; qd < 4; ++qd) {
        union { unsigned short s[8]; f16x8 vec; } u;
#pragma unroll
        for (int j = 0; j < 8; ++j) u.s[j] = ((const unsigned short*)&vpB[j])[qd];
        *(f16x8*)&KA[wB + qd][gB] = u.vec;
      }
    }
  }
  __syncthreads();                              // B3: V^T visible

  {
    f32x4 O[12];
#pragma unroll
    for (int fn = 0; fn < 12; ++fn) O[fn] = (f32x4){0.f, 0.f, 0.f, 0.f};

#pragma unroll
    for (int ks = 0; ks < 6; ++ks) {
      f16x8 pa = *(const f16x8*)&Pf[h0 + lr][ks * 32 + lg * 8];  // A: row h, k = g
#pragma unroll
      for (int fn = 0; fn < 12; ++fn) {
        f16x8 bv_ = *(const f16x8*)&KA[16 * fn + lr][ks * 32 + lg * 8];  // B: col w, k = g
        O[fn] = __builtin_amdgcn_mfma_f32_16x16x32_f16(pa, bv_, O[fn], 0, 0, 0);
      }
    }

#pragma unroll
    for (int fn = 0; fn < 12; ++fn)
#pragma unroll
      for (int r = 0; r < 4; ++r)
        outc[(size_t)(h0 + lg * 4 + r) * 192 + 16 * fn + lr] = O[fn][r];
  }
}

// ---------------------------------------------------------------------------
extern "C" void kernel_launch(void* const* d_in, const int* in_sizes, int n_in,
                              void* d_out, int out_size, void* d_ws, size_t ws_size,
                              hipStream_t stream) {
  const float* query = (const float*)d_in[0];
  const float* key_  = (const float*)d_in[1];
  const float* value = (const float*)d_in[2];
  const float* Wq    = (const float*)d_in[3];
  const float* bq    = (const float*)d_in[4];
  const float* Wk    = (const float*)d_in[5];
  const float* bk    = (const float*)d_in[6];
  const float* Wv    = (const float*)d_in[7];
  const float* bv    = (const float*)d_in[8];
  float* out = (float*)d_out;

  f16* wp  = (f16*)d_ws;                        // 3*65536 fp16 = 384 KB
  f16* qkv = (f16*)((char*)d_ws + 524288);

  convert_w_kernel<<<256, 256, 0, stream>>>(Wq, Wk, Wv, wp);

  const size_t need_fused = 524288 + (size_t)8 * 3 * TS * 2;  // ~453.5 MB
  if (ws_size >= need_fused) {
    // Fused: all 8 batches; conv grid 512 x 27 flat tiles (13824 total).
    conv1x1_kernel<<<512, 512, 0, stream>>>(
        query, key_, value, wp, bq, bk, bv, qkv);
    attn_kernel<<<2048, 768, 0, stream>>>(qkv, out);
  } else {
    // Fallback: per-batch loop; 1728 tiles = 64 blocks x 27.
    for (int b = 0; b < 8; ++b) {
      const size_t off = (size_t)b * TS;
      conv1x1_kernel<<<64, 512, 0, stream>>>(
          query + off, key_ + off, value + off, wp, bq, bk, bv, qkv);
      attn_kernel<<<256, 768, 0, stream>>>(qkv, out + off);
    }
  }
}